// Round 2
// baseline (617.252 us; speedup 1.0000x reference)
//
#include <hip/hip_runtime.h>

// ManifoldConstrainedHyperConnection fused kernel, pipelined.
// x (8192 tokens, 4 streams, 2048 d) fp32; W_router (24,2048); b_router (24); out (8192,4,2048).
//
// NTOK=4 tokens per 256-thread block (grid 2048). Register double-buffer on x:
// token n+1's 32KB x-tile is prefetched before token n's dot loop and stays in
// flight through dots/reduce/sinkhorn/epilogue. Raw `s_waitcnt lgkmcnt(0); s_barrier`
// (NOT __syncthreads, which drains vmcnt(0) and would kill the prefetch) -> one
// barrier per token. Every wave redundantly finalizes logits + sinkhorn (mod-16
// lane groups) so no second barrier / LDS broadcast is needed.

#define NTOK 4
#define EPSV 1e-6f

__global__ __launch_bounds__(256, 4) void mchc_fused(
    const float* __restrict__ x,
    const float* __restrict__ Wr,
    const float* __restrict__ br,
    float* __restrict__ out)
{
    const int tid  = threadIdx.x;     // 0..255
    const int lane = tid & 63;
    const int wave = tid >> 6;
    const int t0   = blockIdx.x * NTOK;

    __shared__ float red[2][4][24];   // [token parity][wave][logit]

    const float4* __restrict__ w4 = (const float4*)Wr;

    // bias preload (uniform + per-lane sinkhorn slot)
    float brp[8];
#pragma unroll
    for (int k = 0; k < 8; ++k) brp[k] = br[k];
    const int l16 = lane & 15;
    const int si = l16 >> 2, sj = l16 & 3;
    const float brw = br[8 + l16];

    float4 xa[4], xb[4];   // current token x
    float4 ya[4], yb[4];   // prefetched next token x
    {
        const float4* xp = (const float4*)(x + (size_t)t0 * 8192);
#pragma unroll
        for (int w = 0; w < 4; ++w) {
            xa[w] = xp[w * 512 + tid];
            xb[w] = xp[w * 512 + 256 + tid];
        }
    }

#pragma unroll
    for (int n = 0; n < NTOK; ++n) {
        const int t = t0 + n;

        // ---- prefetch next token's x (stays in flight across the whole token)
        {
            const int tn = (n + 1 < NTOK) ? (t + 1) : t;   // clamp: L2-hit, harmless
            const float4* xp = (const float4*)(x + (size_t)tn * 8192);
#pragma unroll
            for (int w = 0; w < 4; ++w) {
                ya[w] = xp[w * 512 + tid];
                yb[w] = xp[w * 512 + 256 + tid];
            }
        }

        // ---- stream sum (mean*4; 0.25 folded into logits)
        float4 sa, sb;
        sa.x = xa[0].x + xa[1].x + xa[2].x + xa[3].x;
        sa.y = xa[0].y + xa[1].y + xa[2].y + xa[3].y;
        sa.z = xa[0].z + xa[1].z + xa[2].z + xa[3].z;
        sa.w = xa[0].w + xa[1].w + xa[2].w + xa[3].w;
        sb.x = xb[0].x + xb[1].x + xb[2].x + xb[3].x;
        sb.y = xb[0].y + xb[1].y + xb[2].y + xb[3].y;
        sb.z = xb[0].z + xb[1].z + xb[2].z + xb[3].z;
        sb.w = xb[0].w + xb[1].w + xb[2].w + xb[3].w;

        // ---- 24 router dots, immediate wave-reduce, lane0 -> LDS
#pragma unroll
        for (int k = 0; k < 24; ++k) {
            float4 wa = w4[k * 512 + tid];
            float4 wb = w4[k * 512 + 256 + tid];
            float v = sa.x * wa.x + sa.y * wa.y + sa.z * wa.z + sa.w * wa.w
                    + sb.x * wb.x + sb.y * wb.y + sb.z * wb.z + sb.w * wb.w;
            v += __shfl_xor(v, 1);
            v += __shfl_xor(v, 2);
            v += __shfl_xor(v, 4);
            v += __shfl_xor(v, 8);
            v += __shfl_xor(v, 16);
            v += __shfl_xor(v, 32);
            if (lane == 0) red[n & 1][wave][k] = v;
        }

        // ---- LDS-only barrier: does NOT drain vmcnt (prefetch survives)
        asm volatile("s_waitcnt lgkmcnt(0)\n\ts_barrier" ::: "memory");

        // ---- finalize logits (every wave redundantly; LDS broadcast reads)
        const float* rp = &red[n & 1][0][0];
        float r[8];
#pragma unroll
        for (int k = 0; k < 8; ++k)
            r[k] = 0.25f * (rp[k] + rp[24 + k] + rp[48 + k] + rp[72 + k]) + brp[k];
        float rw = 0.25f * (rp[8 + l16] + rp[32 + l16] + rp[56 + l16] + rp[80 + l16]) + brw;

        // ---- softmaxes (redundant per 16-lane group)
        float mp = fmaxf(fmaxf(r[0], r[1]), fmaxf(r[2], r[3]));
        float e0 = __expf(r[0] - mp), e1 = __expf(r[1] - mp);
        float e2 = __expf(r[2] - mp), e3 = __expf(r[3] - mp);
        float sp = e0 + e1 + e2 + e3;
        float pre_j = ((sj == 0) ? e0 : (sj == 1) ? e1 : (sj == 2) ? e2 : e3) / sp;

        float mq = fmaxf(fmaxf(r[4], r[5]), fmaxf(r[6], r[7]));
        float f0 = __expf(r[4] - mq), f1 = __expf(r[5] - mq);
        float f2 = __expf(r[6] - mq), f3 = __expf(r[7] - mq);
        float sq = f0 + f1 + f2 + f3;
        float post_i = ((si == 0) ? f0 : (si == 1) ? f1 : (si == 2) ? f2 : f3) / sq;

        // ---- sinkhorn on 4x4 (lanes mod 16; shuffles stay within the 16-group)
        float wv = __expf(rw + ((si == sj) ? 2.0f : -2.0f));
#pragma unroll
        for (int it = 0; it < 4; ++it) {
            float rs = wv + __shfl_xor(wv, 1); rs += __shfl_xor(rs, 2);
            wv /= fmaxf(rs, EPSV);
            float cs = wv + __shfl_xor(wv, 4); cs += __shfl_xor(cs, 8);
            wv /= fmaxf(cs, EPSV);
        }
        float Mv = wv + post_i * pre_j;   // fold post[i]*pre[j] into the mix matrix

        // ---- broadcast M within the wave (group 0 holds a full copy)
        float M[16];
#pragma unroll
        for (int m = 0; m < 16; ++m) M[m] = __shfl(Mv, m);

        // ---- apply 4x4 mix to register-resident x, store
        float4* __restrict__ o4 = (float4*)(out + (size_t)t * 8192);
#pragma unroll
        for (int i = 0; i < 4; ++i) {
            float m0 = M[i * 4 + 0], m1 = M[i * 4 + 1], m2 = M[i * 4 + 2], m3 = M[i * 4 + 3];
            float4 oa, ob;
            oa.x = m0 * xa[0].x + m1 * xa[1].x + m2 * xa[2].x + m3 * xa[3].x;
            oa.y = m0 * xa[0].y + m1 * xa[1].y + m2 * xa[2].y + m3 * xa[3].y;
            oa.z = m0 * xa[0].z + m1 * xa[1].z + m2 * xa[2].z + m3 * xa[3].z;
            oa.w = m0 * xa[0].w + m1 * xa[1].w + m2 * xa[2].w + m3 * xa[3].w;
            ob.x = m0 * xb[0].x + m1 * xb[1].x + m2 * xb[2].x + m3 * xb[3].x;
            ob.y = m0 * xb[0].y + m1 * xb[1].y + m2 * xb[2].y + m3 * xb[3].y;
            ob.z = m0 * xb[0].z + m1 * xb[1].z + m2 * xb[2].z + m3 * xb[3].z;
            ob.w = m0 * xb[0].w + m1 * xb[1].w + m2 * xb[2].w + m3 * xb[3].w;
            o4[i * 512 + tid]       = oa;
            o4[i * 512 + 256 + tid] = ob;
        }

        // ---- rotate register buffers (renamed away by full unroll)
#pragma unroll
        for (int w = 0; w < 4; ++w) { xa[w] = ya[w]; xb[w] = yb[w]; }
    }
}

extern "C" void kernel_launch(void* const* d_in, const int* in_sizes, int n_in,
                              void* d_out, int out_size, void* d_ws, size_t ws_size,
                              hipStream_t stream) {
    const float* x  = (const float*)d_in[0];
    const float* Wr = (const float*)d_in[1];
    const float* br = (const float*)d_in[2];
    float* out = (float*)d_out;

    const int tokens = in_sizes[0] / (4 * 2048);   // B*T = 8192
    mchc_fused<<<dim3(tokens / NTOK), dim3(256), 0, stream>>>(x, Wr, br, out);
}